// Round 1
// baseline (812.927 us; speedup 1.0000x reference)
//
#include <hip/hip_runtime.h>
#include <hip/hip_bf16.h>

#define N_NODES 100000
#define EDGES   500000
#define T_TGT   40000
#define NH      8
#define NSEM    128
#define NCLS    8
#define SLOPE   0.01f

// ---------------------------------------------------------------------------
// 1) Type-wise projection GEMM: out[M][64] = A[M][K] @ W[64][K]^T + b
//    BM=64, BN=64, BK=32; 256 threads, 4x4 micro-tile.
// ---------------------------------------------------------------------------
__global__ __launch_bounds__(256) void proj_gemm(const float* __restrict__ A,
        const float* __restrict__ W, const float* __restrict__ bias,
        float* __restrict__ out, int M, int K) {
    __shared__ float As[64][33];
    __shared__ float Ws[64][33];
    int tid = threadIdx.x;
    int r0 = blockIdx.x * 64;
    int ty = tid >> 4;   // 0..15 -> rows ty*4..+4
    int tx = tid & 15;   // cols tx*4..+4
    float acc[4][4] = {};
    for (int kk = 0; kk < K; kk += 32) {
        #pragma unroll
        for (int i = 0; i < 2; i++) {
            int lin = tid + i * 256;            // 0..511
            int row = lin >> 3;                  // 0..63
            int c4 = (lin & 7) * 4;              // 0..28
            float4 v = make_float4(0.f, 0.f, 0.f, 0.f);
            if (r0 + row < M)
                v = *(const float4*)(A + (size_t)(r0 + row) * K + kk + c4);
            As[row][c4 + 0] = v.x; As[row][c4 + 1] = v.y;
            As[row][c4 + 2] = v.z; As[row][c4 + 3] = v.w;
            float4 w = *(const float4*)(W + (size_t)row * K + kk + c4);
            Ws[row][c4 + 0] = w.x; Ws[row][c4 + 1] = w.y;
            Ws[row][c4 + 2] = w.z; Ws[row][c4 + 3] = w.w;
        }
        __syncthreads();
        #pragma unroll
        for (int k = 0; k < 32; k++) {
            float a[4], b[4];
            #pragma unroll
            for (int i = 0; i < 4; i++) a[i] = As[ty * 4 + i][k];
            #pragma unroll
            for (int j = 0; j < 4; j++) b[j] = Ws[tx * 4 + j][k];
            #pragma unroll
            for (int i = 0; i < 4; i++)
                #pragma unroll
                for (int j = 0; j < 4; j++)
                    acc[i][j] = fmaf(a[i], b[j], acc[i][j]);
        }
        __syncthreads();
    }
    float4 b4 = *(const float4*)(bias + tx * 4);
    #pragma unroll
    for (int i = 0; i < 4; i++) {
        int r = r0 + ty * 4 + i;
        if (r < M) {
            float4 o = make_float4(acc[i][0] + b4.x, acc[i][1] + b4.y,
                                   acc[i][2] + b4.z, acc[i][3] + b4.w);
            *(float4*)(out + (size_t)r * 64 + tx * 4) = o;
        }
    }
}

// ---------------------------------------------------------------------------
// 2) Attention projections: proj[n][m*16 + side*8 + h] =
//       sum_d nf[n][d] * node_attention[m][h][side*64 + d]
// ---------------------------------------------------------------------------
__global__ __launch_bounds__(256) void attn_proj(const float* __restrict__ nf,
        const float* __restrict__ na, float* __restrict__ proj) {
    __shared__ float ft[64][65];
    __shared__ float at[32][65];
    int tid = threadIdx.x;
    int n0 = blockIdx.x * 64;
    #pragma unroll
    for (int i = 0; i < 8; i++) {
        int lin = tid + i * 256;       // 0..2047
        int j = lin >> 6, d = lin & 63;
        int m = j >> 4, side = (j >> 3) & 1, h = j & 7;
        at[j][d] = na[m * 1024 + h * 128 + side * 64 + d];
    }
    #pragma unroll
    for (int i = 0; i < 4; i++) {
        int lin = tid + i * 256;       // 0..1023
        int row = lin >> 4;
        int c4 = (lin & 15) * 4;
        int gn = n0 + row;
        float4 v = make_float4(0.f, 0.f, 0.f, 0.f);
        if (gn < N_NODES) v = *(const float4*)(nf + (size_t)gn * 64 + c4);
        ft[row][c4 + 0] = v.x; ft[row][c4 + 1] = v.y;
        ft[row][c4 + 2] = v.z; ft[row][c4 + 3] = v.w;
    }
    __syncthreads();
    int node = tid >> 2;   // 0..63
    int jg = tid & 3;      // output group of 8
    float acc[8] = {};
    for (int d = 0; d < 64; d++) {
        float f = ft[node][d];
        #pragma unroll
        for (int jj = 0; jj < 8; jj++)
            acc[jj] = fmaf(f, at[jg * 8 + jj][d], acc[jj]);
    }
    int gn = n0 + node;
    if (gn < N_NODES) {
        float4 o0 = make_float4(acc[0], acc[1], acc[2], acc[3]);
        float4 o1 = make_float4(acc[4], acc[5], acc[6], acc[7]);
        *(float4*)(proj + (size_t)gn * 32 + jg * 8) = o0;
        *(float4*)(proj + (size_t)gn * 32 + jg * 8 + 4) = o1;
    }
}

// ---------------------------------------------------------------------------
// 3) CSR build helpers
// ---------------------------------------------------------------------------
__global__ void hist_targets(const int* __restrict__ tgt, int* __restrict__ tcnt) {
    int i = blockIdx.x * 256 + threadIdx.x;
    if (i < T_TGT) atomicAdd(&tcnt[tgt[i]], 1);
}

__global__ void hist_edges(const int* __restrict__ mp, const int* __restrict__ tcnt,
                           int* __restrict__ ecnt) {
    int e = blockIdx.x * 256 + threadIdx.x;
    if (e < EDGES) {
        int dst = mp[2 * e + 1];
        if (tcnt[dst] > 0) atomicAdd(&ecnt[dst], 1);
    }
}

// exclusive scan over three length-N arrays; blockIdx.x selects the array.
__global__ __launch_bounds__(1024) void scan3(const int* __restrict__ counts,
        int* __restrict__ offs, int* __restrict__ curs) {
    const int n = N_NODES;
    const int* in = counts + (size_t)blockIdx.x * n;
    int* out = offs + (size_t)blockIdx.x * (n + 1);
    int* cur = curs + (size_t)blockIdx.x * n;
    __shared__ int wsum[17];
    int tid = threadIdx.x, lane = tid & 63, w = tid >> 6;
    int carry = 0;
    for (int base = 0; base < n; base += 1024) {
        int i = base + tid;
        int v = (i < n) ? in[i] : 0;
        int x = v;
        #pragma unroll
        for (int off = 1; off < 64; off <<= 1) {
            int y = __shfl_up(x, off);
            if (lane >= off) x += y;
        }
        if (lane == 63) wsum[w] = x;
        __syncthreads();
        if (w == 0 && lane < 16) {
            int s = wsum[lane];
            int xs = s;
            #pragma unroll
            for (int off = 1; off < 16; off <<= 1) {
                int y = __shfl_up(xs, off);
                if (lane >= off) xs += y;
            }
            wsum[lane] = xs - s;            // exclusive prefix of wave sums
            if (lane == 15) wsum[16] = xs;  // block total
        }
        __syncthreads();
        int excl = carry + wsum[w] + x - v;
        if (i < n) { out[i] = excl; cur[i] = excl; }
        carry += wsum[16];
        __syncthreads();
    }
    if (tid == 0) out[n] = carry;
}

__global__ void scatter_targets(const int* __restrict__ tgt, int* __restrict__ tcur,
                                int* __restrict__ tlist) {
    int i = blockIdx.x * 256 + threadIdx.x;
    if (i < T_TGT) {
        int n = tgt[i];
        int p = atomicAdd(&tcur[n], 1);
        tlist[p] = i;
    }
}

__global__ void scatter_edges(const int* __restrict__ mp, const int* __restrict__ tcnt,
                              int* __restrict__ ecur, int* __restrict__ elist) {
    int e = blockIdx.x * 256 + threadIdx.x;
    if (e < EDGES) {
        int dst = mp[2 * e + 1];
        if (tcnt[dst] > 0) {
            int p = atomicAdd(&ecur[dst], 1);
            elist[p] = mp[2 * e];
        }
    }
}

__global__ void build_ulist(const int* __restrict__ tcnt, int* __restrict__ ulist,
                            int* __restrict__ ucount) {
    int n = blockIdx.x * 256 + threadIdx.x;
    if (n < N_NODES && tcnt[n] > 0) {
        int u = atomicAdd(ucount, 1);
        ulist[u] = n;
    }
}

// ---------------------------------------------------------------------------
// 4) Per-(metapath, target-node) softmax aggregation. One wave per node.
// ---------------------------------------------------------------------------
__global__ __launch_bounds__(256) void agg_kernel(
        const int* __restrict__ ulist, const int* __restrict__ ctrl_i,
        const int* __restrict__ offs,   // [3][N+1]: m0, m1, targets
        const int* __restrict__ esrc,   // [2][E]
        const float* __restrict__ proj, const float* __restrict__ nf,
        const int* __restrict__ tlist,
        float* h0, float* h1) {
    int m = blockIdx.y;
    int wslot = blockIdx.x * 4 + (threadIdx.x >> 6);
    int lane = threadIdx.x & 63;
    int ucount = ctrl_i[0];
    if (wslot >= ucount) return;        // uniform per wave
    int node = ulist[wslot];
    const int* eo = offs + (size_t)m * (N_NODES + 1);
    int e0 = eo[node], e1 = eo[node + 1];
    const int* srcs = esrc + (size_t)m * EDGES;
    const float* pd = proj + (size_t)node * 32 + m * 16;
    float ad[8];
    #pragma unroll
    for (int h = 0; h < 8; h++) ad[h] = pd[h];

    // phase 1: max
    float mx[8];
    #pragma unroll
    for (int h = 0; h < 8; h++) mx[h] = -1e30f;
    for (int b = e0; b < e1; b += 64) {
        int e = b + lane;
        if (e < e1) {
            int s = srcs[e];
            const float* ps = proj + (size_t)s * 32 + m * 16 + 8;
            #pragma unroll
            for (int h = 0; h < 8; h++) {
                float sc = ad[h] + ps[h];
                sc = sc > 0.f ? sc : SLOPE * sc;
                mx[h] = fmaxf(mx[h], sc);
            }
        }
    }
    #pragma unroll
    for (int off = 32; off; off >>= 1)
        #pragma unroll
        for (int h = 0; h < 8; h++) mx[h] = fmaxf(mx[h], __shfl_xor(mx[h], off));

    // phase 2: denominators
    float den[8] = {};
    for (int b = e0; b < e1; b += 64) {
        int e = b + lane;
        if (e < e1) {
            int s = srcs[e];
            const float* ps = proj + (size_t)s * 32 + m * 16 + 8;
            #pragma unroll
            for (int h = 0; h < 8; h++) {
                float sc = ad[h] + ps[h];
                sc = sc > 0.f ? sc : SLOPE * sc;
                den[h] += __expf(sc - mx[h]);
            }
        }
    }
    #pragma unroll
    for (int off = 32; off; off >>= 1)
        #pragma unroll
        for (int h = 0; h < 8; h++) den[h] += __shfl_xor(den[h], off);
    float inv[8];
    #pragma unroll
    for (int h = 0; h < 8; h++) inv[h] = (den[h] > 0.f) ? 1.0f / den[h] : 0.f;

    // phase 3: weighted accumulate (lane = feature dim)
    float acc[8] = {};
    for (int b = e0; b < e1; b += 64) {
        int e = b + lane;
        int cnt = min(64, e1 - b);
        float p[8] = {};
        int s = 0;
        if (e < e1) {
            s = srcs[e];
            const float* ps = proj + (size_t)s * 32 + m * 16 + 8;
            #pragma unroll
            for (int h = 0; h < 8; h++) {
                float sc = ad[h] + ps[h];
                sc = sc > 0.f ? sc : SLOPE * sc;
                p[h] = __expf(sc - mx[h]) * inv[h];
            }
        }
        for (int j = 0; j < cnt; j++) {
            int sj = __shfl(s, j);
            float v = nf[(size_t)sj * 64 + lane];
            #pragma unroll
            for (int h = 0; h < 8; h++) {
                float pj = __shfl(p[h], j);
                acc[h] = fmaf(pj, v, acc[h]);
            }
        }
    }

    // write to every target slot mapping to this node
    const int* to = offs + (size_t)2 * (N_NODES + 1);
    int t0 = to[node], t1 = to[node + 1];
    float* hb = (m == 0) ? h0 : h1;
    for (int ti = t0; ti < t1; ti++) {
        int t = tlist[ti];
        float* dst = hb + (size_t)t * 512;
        #pragma unroll
        for (int h = 0; h < 8; h++) dst[h * 64 + lane] = acc[h];
    }
}

// ---------------------------------------------------------------------------
// 5) Semantic attention scores: scores[m] += sum_{t,s} tanh(h@Wsem^T+bsem)*a_sem
//    GEMM BM=64 targets, BN=128 sem, BK=32; fused tanh + reduction.
// ---------------------------------------------------------------------------
__global__ __launch_bounds__(256) void sem_kernel(
        const float* __restrict__ h0v, const float* __restrict__ h1v,
        const float* __restrict__ Wsem, const float* __restrict__ bsem,
        const float* __restrict__ a_sem, float* __restrict__ scores) {
    __shared__ float As[64][33];
    __shared__ float Bs[128][33];
    __shared__ float red[256];
    int m = blockIdx.y;
    const float* A = ((m == 0) ? h0v : h1v) + (size_t)blockIdx.x * 64 * 512;
    int tid = threadIdx.x;
    int ty = tid >> 5;   // 0..7 -> rows ty*8..+8
    int tx = tid & 31;   // cols tx*4..+4
    float acc[8][4] = {};
    for (int kk = 0; kk < 512; kk += 32) {
        #pragma unroll
        for (int i = 0; i < 2; i++) {
            int lin = tid + i * 256;
            int row = lin >> 3, c4 = (lin & 7) * 4;
            float4 v = *(const float4*)(A + (size_t)row * 512 + kk + c4);
            As[row][c4 + 0] = v.x; As[row][c4 + 1] = v.y;
            As[row][c4 + 2] = v.z; As[row][c4 + 3] = v.w;
        }
        #pragma unroll
        for (int i = 0; i < 4; i++) {
            int lin = tid + i * 256;
            int srow = lin >> 3, c4 = (lin & 7) * 4;
            float4 v = *(const float4*)(Wsem + (size_t)srow * 512 + kk + c4);
            Bs[srow][c4 + 0] = v.x; Bs[srow][c4 + 1] = v.y;
            Bs[srow][c4 + 2] = v.z; Bs[srow][c4 + 3] = v.w;
        }
        __syncthreads();
        #pragma unroll
        for (int k = 0; k < 32; k++) {
            float a[8], b[4];
            #pragma unroll
            for (int i = 0; i < 8; i++) a[i] = As[ty * 8 + i][k];
            #pragma unroll
            for (int j = 0; j < 4; j++) b[j] = Bs[tx * 4 + j][k];
            #pragma unroll
            for (int i = 0; i < 8; i++)
                #pragma unroll
                for (int j = 0; j < 4; j++)
                    acc[i][j] = fmaf(a[i], b[j], acc[i][j]);
        }
        __syncthreads();
    }
    float4 bs4 = *(const float4*)(bsem + tx * 4);
    float4 as4 = *(const float4*)(a_sem + tx * 4);
    float tot = 0.f;
    #pragma unroll
    for (int i = 0; i < 8; i++) {
        tot += tanhf(acc[i][0] + bs4.x) * as4.x;
        tot += tanhf(acc[i][1] + bs4.y) * as4.y;
        tot += tanhf(acc[i][2] + bs4.z) * as4.z;
        tot += tanhf(acc[i][3] + bs4.w) * as4.w;
    }
    red[tid] = tot;
    __syncthreads();
    for (int s = 128; s; s >>= 1) {
        if (tid < s) red[tid] += red[tid + s];
        __syncthreads();
    }
    if (tid == 0) atomicAdd(&scores[m], red[0]);
}

__global__ void beta_kernel(const float* __restrict__ scores, float* __restrict__ beta) {
    if (threadIdx.x == 0) {
        float s0 = scores[0] / (float)T_TGT;
        float s1 = scores[1] / (float)T_TGT;
        float mx = fmaxf(s0, s1);
        float e0 = __expf(s0 - mx), e1 = __expf(s1 - mx);
        float inv = 1.f / (e0 + e1);
        beta[0] = e0 * inv;
        beta[1] = e1 * inv;
    }
}

// ---------------------------------------------------------------------------
// 6) embeddings = b0*h0 + b1*h1 (in place over h0 region) + cls logits.
//    NOTE: h0 aliases out_emb — intentional, read-before-write per thread.
// ---------------------------------------------------------------------------
__global__ __launch_bounds__(256) void emb_cls(
        const float* h0, const float* h1,
        const float* __restrict__ beta, const float* __restrict__ Wcls,
        const float* __restrict__ bcls, float* out_cls, float* out_emb) {
    __shared__ float Wl[8 * 512];
    int tid = threadIdx.x;
    #pragma unroll
    for (int i = 0; i < 16; i++) Wl[tid + i * 256] = Wcls[tid + i * 256];
    __syncthreads();
    int t = blockIdx.x * 4 + (tid >> 6);
    int lane = tid & 63;
    float b0 = beta[0], b1 = beta[1];
    const float* p0 = h0 + (size_t)t * 512;
    const float* p1 = h1 + (size_t)t * 512;
    float e[8];
    #pragma unroll
    for (int q = 0; q < 8; q++) e[q] = b0 * p0[q * 64 + lane] + b1 * p1[q * 64 + lane];
    #pragma unroll
    for (int q = 0; q < 8; q++) out_emb[(size_t)t * 512 + q * 64 + lane] = e[q];
    float pc[8];
    #pragma unroll
    for (int c = 0; c < 8; c++) {
        float s = 0.f;
        #pragma unroll
        for (int q = 0; q < 8; q++) s = fmaf(e[q], Wl[c * 512 + q * 64 + lane], s);
        pc[c] = s;
    }
    #pragma unroll
    for (int off = 32; off; off >>= 1)
        #pragma unroll
        for (int c = 0; c < 8; c++) pc[c] += __shfl_xor(pc[c], off);
    if (lane == 0) {
        #pragma unroll
        for (int c = 0; c < 8; c++) out_cls[(size_t)t * 8 + c] = pc[c] + bcls[c];
    }
}

// ---------------------------------------------------------------------------
extern "C" void kernel_launch(void* const* d_in, const int* in_sizes, int n_in,
                              void* d_out, int out_size, void* d_ws, size_t ws_size,
                              hipStream_t stream) {
    const int* target = (const int*)d_in[0];
    const int* mp0 = (const int*)d_in[1];
    const int* mp1 = (const int*)d_in[2];
    // d_in[3] node_type_mapping unused (types are contiguous ranges)
    const float* feat0 = (const float*)d_in[4];
    const float* W0 = (const float*)d_in[5];
    const float* b0 = (const float*)d_in[6];
    const float* feat1 = (const float*)d_in[7];
    const float* W1 = (const float*)d_in[8];
    const float* b1 = (const float*)d_in[9];
    const float* feat2 = (const float*)d_in[10];
    const float* W2 = (const float*)d_in[11];
    const float* b2 = (const float*)d_in[12];
    const float* natt = (const float*)d_in[13];
    const float* Wsem = (const float*)d_in[14];
    const float* bsem = (const float*)d_in[15];
    const float* asem = (const float*)d_in[16];
    const float* Wcls = (const float*)d_in[17];
    const float* bcls = (const float*)d_in[18];

    char* ws = (char*)d_ws;
    size_t off = 0;
    auto alloc = [&](size_t bytes) -> void* {
        void* p = ws + off;
        off += (bytes + 15) & ~(size_t)15;
        return p;
    };
    float* nf    = (float*)alloc((size_t)N_NODES * 64 * 4);   // 25.6 MB
    float* proj  = (float*)alloc((size_t)N_NODES * 32 * 4);   // 12.8 MB
    int* counts3 = (int*)alloc((size_t)3 * N_NODES * 4);
    int* offs3   = (int*)alloc((size_t)3 * (N_NODES + 1) * 4);
    int* curs3   = (int*)alloc((size_t)3 * N_NODES * 4);
    int* tlist   = (int*)alloc((size_t)T_TGT * 4);
    int* ulist   = (int*)alloc((size_t)N_NODES * 4);
    int* esrc    = (int*)alloc((size_t)2 * EDGES * 4);
    int* ctrl    = (int*)alloc(64);
    float* h1    = (float*)alloc((size_t)T_TGT * 512 * 4);    // 81.9 MB
    if (off > ws_size) return;  // ws too small: fail loudly (output stays poisoned)

    float* out_cls = (float*)d_out;
    float* out_emb = out_cls + (size_t)T_TGT * NCLS;
    float* h0 = out_emb;                    // h0 lives in the output embeddings region
    float* ctrl_f = (float*)ctrl;
    float* scores = ctrl_f + 1;             // ctrl[0] = ucount
    float* beta = ctrl_f + 3;

    hipMemsetAsync(counts3, 0, (size_t)3 * N_NODES * 4, stream);
    hipMemsetAsync(ctrl, 0, 64, stream);

    proj_gemm<<<dim3(625), 256, 0, stream>>>(feat0, W0, b0, nf, 40000, 512);
    proj_gemm<<<dim3(625), 256, 0, stream>>>(feat1, W1, b1, nf + (size_t)40000 * 64, 40000, 256);
    proj_gemm<<<dim3(313), 256, 0, stream>>>(feat2, W2, b2, nf + (size_t)80000 * 64, 20000, 128);
    attn_proj<<<dim3(1563), 256, 0, stream>>>(nf, natt, proj);

    hist_targets<<<dim3(157), 256, 0, stream>>>(target, counts3 + 2 * N_NODES);
    hist_edges<<<dim3(1954), 256, 0, stream>>>(mp0, counts3 + 2 * N_NODES, counts3);
    hist_edges<<<dim3(1954), 256, 0, stream>>>(mp1, counts3 + 2 * N_NODES, counts3 + N_NODES);
    scan3<<<dim3(3), 1024, 0, stream>>>(counts3, offs3, curs3);
    scatter_targets<<<dim3(157), 256, 0, stream>>>(target, curs3 + 2 * N_NODES, tlist);
    scatter_edges<<<dim3(1954), 256, 0, stream>>>(mp0, counts3 + 2 * N_NODES, curs3, esrc);
    scatter_edges<<<dim3(1954), 256, 0, stream>>>(mp1, counts3 + 2 * N_NODES, curs3 + N_NODES, esrc + EDGES);
    build_ulist<<<dim3(391), 256, 0, stream>>>(counts3 + 2 * N_NODES, ulist, ctrl);

    agg_kernel<<<dim3(10000, 2), 256, 0, stream>>>(ulist, ctrl, offs3, esrc, proj, nf, tlist, h0, h1);
    sem_kernel<<<dim3(625, 2), 256, 0, stream>>>(h0, h1, Wsem, bsem, asem, scores);
    beta_kernel<<<dim3(1), 64, 0, stream>>>(scores, beta);
    emb_cls<<<dim3(10000), 256, 0, stream>>>(h0, h1, beta, Wcls, bcls, out_cls, out_emb);
}

// Round 2
// 686.140 us; speedup vs baseline: 1.1848x; 1.1848x over previous
//
#include <hip/hip_runtime.h>
#include <hip/hip_bf16.h>

#define N_NODES 100000
#define EDGES   500000
#define T_TGT   40000
#define NH      8
#define NSEM    128
#define NCLS    8
#define SLOPE   0.01f

typedef __attribute__((ext_vector_type(8))) __bf16 bf16x8;
typedef __attribute__((ext_vector_type(4))) float f32x4;

// ---------------------------------------------------------------------------
// 1) Type-wise projection GEMM: out[M][64] = A[M][K] @ W[64][K]^T + b
//    BM=64, BN=64, BK=32; 256 threads, 4x4 micro-tile. (f32 — feeds embeddings)
// ---------------------------------------------------------------------------
__global__ __launch_bounds__(256) void proj_gemm(const float* __restrict__ A,
        const float* __restrict__ W, const float* __restrict__ bias,
        float* __restrict__ out, int M, int K) {
    __shared__ float As[64][33];
    __shared__ float Ws[64][33];
    int tid = threadIdx.x;
    int r0 = blockIdx.x * 64;
    int ty = tid >> 4;   // 0..15 -> rows ty*4..+4
    int tx = tid & 15;   // cols tx*4..+4
    float acc[4][4] = {};
    for (int kk = 0; kk < K; kk += 32) {
        #pragma unroll
        for (int i = 0; i < 2; i++) {
            int lin = tid + i * 256;            // 0..511
            int row = lin >> 3;                  // 0..63
            int c4 = (lin & 7) * 4;              // 0..28
            float4 v = make_float4(0.f, 0.f, 0.f, 0.f);
            if (r0 + row < M)
                v = *(const float4*)(A + (size_t)(r0 + row) * K + kk + c4);
            As[row][c4 + 0] = v.x; As[row][c4 + 1] = v.y;
            As[row][c4 + 2] = v.z; As[row][c4 + 3] = v.w;
            float4 w = *(const float4*)(W + (size_t)row * K + kk + c4);
            Ws[row][c4 + 0] = w.x; Ws[row][c4 + 1] = w.y;
            Ws[row][c4 + 2] = w.z; Ws[row][c4 + 3] = w.w;
        }
        __syncthreads();
        #pragma unroll
        for (int k = 0; k < 32; k++) {
            float a[4], b[4];
            #pragma unroll
            for (int i = 0; i < 4; i++) a[i] = As[ty * 4 + i][k];
            #pragma unroll
            for (int j = 0; j < 4; j++) b[j] = Ws[tx * 4 + j][k];
            #pragma unroll
            for (int i = 0; i < 4; i++)
                #pragma unroll
                for (int j = 0; j < 4; j++)
                    acc[i][j] = fmaf(a[i], b[j], acc[i][j]);
        }
        __syncthreads();
    }
    float4 b4 = *(const float4*)(bias + tx * 4);
    #pragma unroll
    for (int i = 0; i < 4; i++) {
        int r = r0 + ty * 4 + i;
        if (r < M) {
            float4 o = make_float4(acc[i][0] + b4.x, acc[i][1] + b4.y,
                                   acc[i][2] + b4.z, acc[i][3] + b4.w);
            *(float4*)(out + (size_t)r * 64 + tx * 4) = o;
        }
    }
}

// ---------------------------------------------------------------------------
// 2) Attention projections: proj[n][m*16 + side*8 + h] =
//       sum_d nf[n][d] * node_attention[m][h][side*64 + d]
// ---------------------------------------------------------------------------
__global__ __launch_bounds__(256) void attn_proj(const float* __restrict__ nf,
        const float* __restrict__ na, float* __restrict__ proj) {
    __shared__ float ft[64][65];
    __shared__ float at[32][65];
    int tid = threadIdx.x;
    int n0 = blockIdx.x * 64;
    #pragma unroll
    for (int i = 0; i < 8; i++) {
        int lin = tid + i * 256;       // 0..2047
        int j = lin >> 6, d = lin & 63;
        int m = j >> 4, side = (j >> 3) & 1, h = j & 7;
        at[j][d] = na[m * 1024 + h * 128 + side * 64 + d];
    }
    #pragma unroll
    for (int i = 0; i < 4; i++) {
        int lin = tid + i * 256;       // 0..1023
        int row = lin >> 4;
        int c4 = (lin & 15) * 4;
        int gn = n0 + row;
        float4 v = make_float4(0.f, 0.f, 0.f, 0.f);
        if (gn < N_NODES) v = *(const float4*)(nf + (size_t)gn * 64 + c4);
        ft[row][c4 + 0] = v.x; ft[row][c4 + 1] = v.y;
        ft[row][c4 + 2] = v.z; ft[row][c4 + 3] = v.w;
    }
    __syncthreads();
    int node = tid >> 2;   // 0..63
    int jg = tid & 3;      // output group of 8
    float acc[8] = {};
    for (int d = 0; d < 64; d++) {
        float f = ft[node][d];
        #pragma unroll
        for (int jj = 0; jj < 8; jj++)
            acc[jj] = fmaf(f, at[jg * 8 + jj][d], acc[jj]);
    }
    int gn = n0 + node;
    if (gn < N_NODES) {
        float4 o0 = make_float4(acc[0], acc[1], acc[2], acc[3]);
        float4 o1 = make_float4(acc[4], acc[5], acc[6], acc[7]);
        *(float4*)(proj + (size_t)gn * 32 + jg * 8) = o0;
        *(float4*)(proj + (size_t)gn * 32 + jg * 8 + 4) = o1;
    }
}

// ---------------------------------------------------------------------------
// 3) CSR build helpers
// ---------------------------------------------------------------------------
__global__ void hist_targets(const int* __restrict__ tgt, int* __restrict__ tcnt) {
    int i = blockIdx.x * 256 + threadIdx.x;
    if (i < T_TGT) atomicAdd(&tcnt[tgt[i]], 1);
}

__global__ void hist_edges(const int* __restrict__ mp, const int* __restrict__ tcnt,
                           int* __restrict__ ecnt) {
    int e = blockIdx.x * 256 + threadIdx.x;
    if (e < EDGES) {
        int dst = mp[2 * e + 1];
        if (tcnt[dst] > 0) atomicAdd(&ecnt[dst], 1);
    }
}

// exclusive scan over three length-N arrays; blockIdx.x selects the array.
__global__ __launch_bounds__(1024) void scan3(const int* __restrict__ counts,
        int* __restrict__ offs, int* __restrict__ curs) {
    const int n = N_NODES;
    const int* in = counts + (size_t)blockIdx.x * n;
    int* out = offs + (size_t)blockIdx.x * (n + 1);
    int* cur = curs + (size_t)blockIdx.x * n;
    __shared__ int wsum[17];
    int tid = threadIdx.x, lane = tid & 63, w = tid >> 6;
    int carry = 0;
    for (int base = 0; base < n; base += 1024) {
        int i = base + tid;
        int v = (i < n) ? in[i] : 0;
        int x = v;
        #pragma unroll
        for (int off = 1; off < 64; off <<= 1) {
            int y = __shfl_up(x, off);
            if (lane >= off) x += y;
        }
        if (lane == 63) wsum[w] = x;
        __syncthreads();
        if (w == 0 && lane < 16) {
            int s = wsum[lane];
            int xs = s;
            #pragma unroll
            for (int off = 1; off < 16; off <<= 1) {
                int y = __shfl_up(xs, off);
                if (lane >= off) xs += y;
            }
            wsum[lane] = xs - s;            // exclusive prefix of wave sums
            if (lane == 15) wsum[16] = xs;  // block total
        }
        __syncthreads();
        int excl = carry + wsum[w] + x - v;
        if (i < n) { out[i] = excl; cur[i] = excl; }
        carry += wsum[16];
        __syncthreads();
    }
    if (tid == 0) out[n] = carry;
}

__global__ void scatter_targets(const int* __restrict__ tgt, int* __restrict__ tcur,
                                int* __restrict__ tlist) {
    int i = blockIdx.x * 256 + threadIdx.x;
    if (i < T_TGT) {
        int n = tgt[i];
        int p = atomicAdd(&tcur[n], 1);
        tlist[p] = i;
    }
}

__global__ void scatter_edges(const int* __restrict__ mp, const int* __restrict__ tcnt,
                              int* __restrict__ ecur, int* __restrict__ elist) {
    int e = blockIdx.x * 256 + threadIdx.x;
    if (e < EDGES) {
        int dst = mp[2 * e + 1];
        if (tcnt[dst] > 0) {
            int p = atomicAdd(&ecur[dst], 1);
            elist[p] = mp[2 * e];
        }
    }
}

__global__ void build_ulist(const int* __restrict__ tcnt, int* __restrict__ ulist,
                            int* __restrict__ ucount) {
    int n = blockIdx.x * 256 + threadIdx.x;
    if (n < N_NODES && tcnt[n] > 0) {
        int u = atomicAdd(ucount, 1);
        ulist[u] = n;
    }
}

__global__ void cvt_bf16(const float* __restrict__ in, __bf16* __restrict__ out, int n) {
    int i = blockIdx.x * 256 + threadIdx.x;
    if (i < n) out[i] = (__bf16)in[i];
}

// ---------------------------------------------------------------------------
// 4) Per-(metapath, target-node) softmax aggregation. One wave per node.
//    h output stored as bf16 (feeds sem MFMA + emb_cls; 0.4% rounding ok).
// ---------------------------------------------------------------------------
__global__ __launch_bounds__(256) void agg_kernel(
        const int* __restrict__ ulist, const int* __restrict__ ctrl_i,
        const int* __restrict__ offs,   // [3][N+1]: m0, m1, targets
        const int* __restrict__ esrc,   // [2][E]
        const float* __restrict__ proj, const float* __restrict__ nf,
        const int* __restrict__ tlist,
        __bf16* hb0, __bf16* hb1) {
    int m = blockIdx.y;
    int wslot = blockIdx.x * 4 + (threadIdx.x >> 6);
    int lane = threadIdx.x & 63;
    int ucount = ctrl_i[0];
    if (wslot >= ucount) return;        // uniform per wave
    int node = ulist[wslot];
    const int* eo = offs + (size_t)m * (N_NODES + 1);
    int e0 = eo[node], e1 = eo[node + 1];
    const int* srcs = esrc + (size_t)m * EDGES;
    const float* pd = proj + (size_t)node * 32 + m * 16;
    float ad[8];
    #pragma unroll
    for (int h = 0; h < 8; h++) ad[h] = pd[h];

    // phase 1: max
    float mx[8];
    #pragma unroll
    for (int h = 0; h < 8; h++) mx[h] = -1e30f;
    for (int b = e0; b < e1; b += 64) {
        int e = b + lane;
        if (e < e1) {
            int s = srcs[e];
            const float* ps = proj + (size_t)s * 32 + m * 16 + 8;
            #pragma unroll
            for (int h = 0; h < 8; h++) {
                float sc = ad[h] + ps[h];
                sc = sc > 0.f ? sc : SLOPE * sc;
                mx[h] = fmaxf(mx[h], sc);
            }
        }
    }
    #pragma unroll
    for (int off = 32; off; off >>= 1)
        #pragma unroll
        for (int h = 0; h < 8; h++) mx[h] = fmaxf(mx[h], __shfl_xor(mx[h], off));

    // phase 2: denominators
    float den[8] = {};
    for (int b = e0; b < e1; b += 64) {
        int e = b + lane;
        if (e < e1) {
            int s = srcs[e];
            const float* ps = proj + (size_t)s * 32 + m * 16 + 8;
            #pragma unroll
            for (int h = 0; h < 8; h++) {
                float sc = ad[h] + ps[h];
                sc = sc > 0.f ? sc : SLOPE * sc;
                den[h] += __expf(sc - mx[h]);
            }
        }
    }
    #pragma unroll
    for (int off = 32; off; off >>= 1)
        #pragma unroll
        for (int h = 0; h < 8; h++) den[h] += __shfl_xor(den[h], off);
    float inv[8];
    #pragma unroll
    for (int h = 0; h < 8; h++) inv[h] = (den[h] > 0.f) ? 1.0f / den[h] : 0.f;

    // phase 3: weighted accumulate (lane = feature dim)
    float acc[8] = {};
    for (int b = e0; b < e1; b += 64) {
        int e = b + lane;
        int cnt = min(64, e1 - b);
        float p[8] = {};
        int s = 0;
        if (e < e1) {
            s = srcs[e];
            const float* ps = proj + (size_t)s * 32 + m * 16 + 8;
            #pragma unroll
            for (int h = 0; h < 8; h++) {
                float sc = ad[h] + ps[h];
                sc = sc > 0.f ? sc : SLOPE * sc;
                p[h] = __expf(sc - mx[h]) * inv[h];
            }
        }
        for (int j = 0; j < cnt; j++) {
            int sj = __shfl(s, j);
            float v = nf[(size_t)sj * 64 + lane];
            #pragma unroll
            for (int h = 0; h < 8; h++) {
                float pj = __shfl(p[h], j);
                acc[h] = fmaf(pj, v, acc[h]);
            }
        }
    }

    // write (bf16) to every target slot mapping to this node
    const int* to = offs + (size_t)2 * (N_NODES + 1);
    int t0 = to[node], t1 = to[node + 1];
    __bf16* hb = (m == 0) ? hb0 : hb1;
    for (int ti = t0; ti < t1; ti++) {
        int t = tlist[ti];
        __bf16* dst = hb + (size_t)t * 512;
        #pragma unroll
        for (int h = 0; h < 8; h++) dst[h * 64 + lane] = (__bf16)acc[h];
    }
}

// ---------------------------------------------------------------------------
// 5) Semantic attention scores via bf16 MFMA, no LDS for the GEMM.
//    Block: 4 waves; wave w covers cols [w*32, w*32+32), rows = 64 per block.
//    scores[m] += sum tanh(h@Wsem^T + bsem) * a_sem   (D layout: col=lane&15)
// ---------------------------------------------------------------------------
__global__ __launch_bounds__(256) void sem_mfma(
        const __bf16* __restrict__ hb,   // [2][T][512]
        const __bf16* __restrict__ Wb,   // [128][512]
        const float* __restrict__ bsem, const float* __restrict__ a_sem,
        float* __restrict__ scores) {
    int m = blockIdx.y;
    const __bf16* A = hb + (size_t)m * T_TGT * 512 + (size_t)blockIdx.x * 64 * 512;
    int wave = threadIdx.x >> 6, lane = threadIdx.x & 63;
    int n0 = wave * 32;
    int mrow = lane & 15;
    int koff0 = (lane >> 4) * 8;
    f32x4 acc[4][2] = {};
    for (int k0 = 0; k0 < 512; k0 += 32) {
        int koff = k0 + koff0;
        bf16x8 a[4], b[2];
        #pragma unroll
        for (int r = 0; r < 4; r++)
            a[r] = *(const bf16x8*)(A + (size_t)(r * 16 + mrow) * 512 + koff);
        #pragma unroll
        for (int c = 0; c < 2; c++)
            b[c] = *(const bf16x8*)(Wb + (size_t)(n0 + c * 16 + mrow) * 512 + koff);
        #pragma unroll
        for (int r = 0; r < 4; r++)
            #pragma unroll
            for (int c = 0; c < 2; c++)
                acc[r][c] = __builtin_amdgcn_mfma_f32_16x16x32_bf16(a[r], b[c], acc[r][c], 0, 0, 0);
    }
    float tot = 0.f;
    #pragma unroll
    for (int c = 0; c < 2; c++) {
        int col = n0 + c * 16 + (lane & 15);
        float bs = bsem[col], as = a_sem[col];
        #pragma unroll
        for (int r = 0; r < 4; r++)
            #pragma unroll
            for (int j = 0; j < 4; j++) {
                float x = acc[r][c][j] + bs;
                float th = 1.f - 2.f / (__expf(2.f * x) + 1.f);  // tanh, inf-safe
                tot += th * as;
            }
    }
    __shared__ float red[256];
    red[threadIdx.x] = tot;
    __syncthreads();
    for (int s = 128; s; s >>= 1) {
        if (threadIdx.x < s) red[threadIdx.x] += red[threadIdx.x + s];
        __syncthreads();
    }
    if (threadIdx.x == 0) atomicAdd(&scores[m], red[0]);
}

__global__ void beta_kernel(const float* __restrict__ scores, float* __restrict__ beta) {
    if (threadIdx.x == 0) {
        float s0 = scores[0] / (float)T_TGT;
        float s1 = scores[1] / (float)T_TGT;
        float mx = fmaxf(s0, s1);
        float e0 = __expf(s0 - mx), e1 = __expf(s1 - mx);
        float inv = 1.f / (e0 + e1);
        beta[0] = e0 * inv;
        beta[1] = e1 * inv;
    }
}

// ---------------------------------------------------------------------------
// 6) embeddings = b0*h0 + b1*h1 (bf16 in, f32 out) + cls logits.
//    Lane l covers k in [8l, 8l+8): bf16x8 loads, float4 stores, all coalesced.
// ---------------------------------------------------------------------------
__global__ __launch_bounds__(256) void emb_cls(
        const __bf16* __restrict__ hb0, const __bf16* __restrict__ hb1,
        const float* __restrict__ beta, const float* __restrict__ Wcls,
        const float* __restrict__ bcls, float* out_cls, float* out_emb) {
    __shared__ float Wl[8 * 512];
    int tid = threadIdx.x;
    #pragma unroll
    for (int i = 0; i < 16; i++) Wl[tid + i * 256] = Wcls[tid + i * 256];
    __syncthreads();
    int t = blockIdx.x * 4 + (tid >> 6);
    int lane = tid & 63;
    float b0 = beta[0], b1 = beta[1];
    bf16x8 v0 = *(const bf16x8*)(hb0 + (size_t)t * 512 + lane * 8);
    bf16x8 v1 = *(const bf16x8*)(hb1 + (size_t)t * 512 + lane * 8);
    float e[8];
    #pragma unroll
    for (int j = 0; j < 8; j++) e[j] = b0 * (float)v0[j] + b1 * (float)v1[j];
    float* ep = out_emb + (size_t)t * 512 + lane * 8;
    *(float4*)(ep + 0) = make_float4(e[0], e[1], e[2], e[3]);
    *(float4*)(ep + 4) = make_float4(e[4], e[5], e[6], e[7]);
    float pc[8];
    #pragma unroll
    for (int c = 0; c < 8; c++) {
        float4 w0 = *(const float4*)(Wl + c * 512 + lane * 8);
        float4 w1 = *(const float4*)(Wl + c * 512 + lane * 8 + 4);
        pc[c] = e[0] * w0.x + e[1] * w0.y + e[2] * w0.z + e[3] * w0.w
              + e[4] * w1.x + e[5] * w1.y + e[6] * w1.z + e[7] * w1.w;
    }
    #pragma unroll
    for (int off = 32; off; off >>= 1)
        #pragma unroll
        for (int c = 0; c < 8; c++) pc[c] += __shfl_xor(pc[c], off);
    if (lane == 0) {
        #pragma unroll
        for (int c = 0; c < 8; c++) out_cls[(size_t)t * 8 + c] = pc[c] + bcls[c];
    }
}

// ---------------------------------------------------------------------------
extern "C" void kernel_launch(void* const* d_in, const int* in_sizes, int n_in,
                              void* d_out, int out_size, void* d_ws, size_t ws_size,
                              hipStream_t stream) {
    const int* target = (const int*)d_in[0];
    const int* mp0 = (const int*)d_in[1];
    const int* mp1 = (const int*)d_in[2];
    // d_in[3] node_type_mapping unused (types are contiguous ranges)
    const float* feat0 = (const float*)d_in[4];
    const float* W0 = (const float*)d_in[5];
    const float* b0 = (const float*)d_in[6];
    const float* feat1 = (const float*)d_in[7];
    const float* W1 = (const float*)d_in[8];
    const float* b1 = (const float*)d_in[9];
    const float* feat2 = (const float*)d_in[10];
    const float* W2 = (const float*)d_in[11];
    const float* b2 = (const float*)d_in[12];
    const float* natt = (const float*)d_in[13];
    const float* Wsem = (const float*)d_in[14];
    const float* bsem = (const float*)d_in[15];
    const float* asem = (const float*)d_in[16];
    const float* Wcls = (const float*)d_in[17];
    const float* bcls = (const float*)d_in[18];

    char* ws = (char*)d_ws;
    size_t off = 0;
    auto alloc = [&](size_t bytes) -> void* {
        void* p = ws + off;
        off += (bytes + 15) & ~(size_t)15;
        return p;
    };
    float* nf    = (float*)alloc((size_t)N_NODES * 64 * 4);   // 25.6 MB
    float* proj  = (float*)alloc((size_t)N_NODES * 32 * 4);   // 12.8 MB
    int* counts3 = (int*)alloc((size_t)3 * N_NODES * 4);
    int* offs3   = (int*)alloc((size_t)3 * (N_NODES + 1) * 4);
    int* curs3   = (int*)alloc((size_t)3 * N_NODES * 4);
    int* tlist   = (int*)alloc((size_t)T_TGT * 4);
    int* ulist   = (int*)alloc((size_t)N_NODES * 4);
    int* esrc    = (int*)alloc((size_t)2 * EDGES * 4);
    int* ctrl    = (int*)alloc(64);
    __bf16* Wsem_b = (__bf16*)alloc((size_t)NSEM * 512 * 2);  // 128 KB
    __bf16* hb   = (__bf16*)alloc((size_t)2 * T_TGT * 512 * 2); // 81.9 MB
    if (off > ws_size) return;  // ws too small: fail loudly (output stays poisoned)

    float* out_cls = (float*)d_out;
    float* out_emb = out_cls + (size_t)T_TGT * NCLS;
    __bf16* hb0 = hb;
    __bf16* hb1 = hb + (size_t)T_TGT * 512;
    float* ctrl_f = (float*)ctrl;
    float* scores = ctrl_f + 1;             // ctrl[0] = ucount
    float* beta = ctrl_f + 3;

    hipMemsetAsync(counts3, 0, (size_t)3 * N_NODES * 4, stream);
    hipMemsetAsync(ctrl, 0, 64, stream);

    proj_gemm<<<dim3(625), 256, 0, stream>>>(feat0, W0, b0, nf, 40000, 512);
    proj_gemm<<<dim3(625), 256, 0, stream>>>(feat1, W1, b1, nf + (size_t)40000 * 64, 40000, 256);
    proj_gemm<<<dim3(313), 256, 0, stream>>>(feat2, W2, b2, nf + (size_t)80000 * 64, 20000, 128);
    attn_proj<<<dim3(1563), 256, 0, stream>>>(nf, natt, proj);
    cvt_bf16<<<dim3(256), 256, 0, stream>>>(Wsem, Wsem_b, NSEM * 512);

    hist_targets<<<dim3(157), 256, 0, stream>>>(target, counts3 + 2 * N_NODES);
    hist_edges<<<dim3(1954), 256, 0, stream>>>(mp0, counts3 + 2 * N_NODES, counts3);
    hist_edges<<<dim3(1954), 256, 0, stream>>>(mp1, counts3 + 2 * N_NODES, counts3 + N_NODES);
    scan3<<<dim3(3), 1024, 0, stream>>>(counts3, offs3, curs3);
    scatter_targets<<<dim3(157), 256, 0, stream>>>(target, curs3 + 2 * N_NODES, tlist);
    scatter_edges<<<dim3(1954), 256, 0, stream>>>(mp0, counts3 + 2 * N_NODES, curs3, esrc);
    scatter_edges<<<dim3(1954), 256, 0, stream>>>(mp1, counts3 + 2 * N_NODES, curs3 + N_NODES, esrc + EDGES);
    build_ulist<<<dim3(391), 256, 0, stream>>>(counts3 + 2 * N_NODES, ulist, ctrl);

    agg_kernel<<<dim3(10000, 2), 256, 0, stream>>>(ulist, ctrl, offs3, esrc, proj, nf, tlist, hb0, hb1);
    sem_mfma<<<dim3(625, 2), 256, 0, stream>>>(hb, Wsem_b, bsem, asem, scores);
    beta_kernel<<<dim3(1), 64, 0, stream>>>(scores, beta);
    emb_cls<<<dim3(10000), 256, 0, stream>>>(hb0, hb1, beta, Wcls, bcls, out_cls, out_emb);
}